// Round 6
// baseline (814.194 us; speedup 1.0000x reference)
//
#include <hip/hip_runtime.h>
#include <hip/hip_bf16.h>
#include <math.h>

#define EPS 1e-5f

typedef __hip_bfloat16 bf16;
typedef short s16x8 __attribute__((ext_vector_type(8)));
typedef float f32x4 __attribute__((ext_vector_type(4)));

constexpr int ilog2c(int v) { return v <= 1 ? 0 : 1 + ilog2c(v >> 1); }

__device__ __forceinline__ float ldin(const void* p, size_t i, int isbf) {
    return isbf ? __bfloat162float(((const bf16*)p)[i]) : ((const float*)p)[i];
}
__device__ __forceinline__ float b2f_bits(short s) {
    unsigned u = ((unsigned)(unsigned short)s) << 16;
    return __builtin_bit_cast(float, u);
}
// packed square of 2 bf16 in one dword, round-half-up (x^2 >= 0)
__device__ __forceinline__ unsigned sqpk1(unsigned w) {
    float lo = __builtin_bit_cast(float, w << 16);
    float hi = __builtin_bit_cast(float, w & 0xffff0000u);
    lo *= lo; hi *= hi;
    unsigned ul = __builtin_bit_cast(unsigned, lo) + 0x8000u;
    unsigned uh = __builtin_bit_cast(unsigned, hi) + 0x8000u;
    return __builtin_amdgcn_perm(uh, ul, 0x07060302);  // [uh.b3 uh.b2 ul.b3 ul.b2]
}
__device__ __forceinline__ uint4 sqpk4(uint4 u) {
    uint4 r;
    r.x = sqpk1(u.x); r.y = sqpk1(u.y); r.z = sqpk1(u.z); r.w = sqpk1(u.w);
    return r;
}

// async global->LDS DMA, 16B/lane; LDS dest = wave-uniform base + lane*16
__device__ __forceinline__ void dma16(const void* g, void* l) {
    __builtin_amdgcn_global_load_lds(
        (const __attribute__((address_space(1))) void*)g,
        (__attribute__((address_space(3))) void*)l, 16, 0, 0);
}

// ---------------------------------------------------------------------------
// dtype sniff (f32 vs bf16-packed inputs); flags[0]=1 => bf16
// also zeroes the OOB guard pages of the two activation regions
// ---------------------------------------------------------------------------
__global__ __launch_bounds__(64) void detect_kernel(const void* __restrict__ x,
                                                    int* __restrict__ flags,
                                                    char* __restrict__ gA,
                                                    char* __restrict__ gB) {
    const unsigned* w = (const unsigned*)x;
    unsigned word = w[threadIdx.x];
    int e = (word >> 23) & 0xFF;
    bool ok = (word == 0u) || (e >= 0x70 && e <= 0x8E);
    unsigned long long m = __ballot(ok);
    if (threadIdx.x == 0) flags[0] = (__popcll(m) >= 32) ? 0 : 1;
    if (threadIdx.x < 16) ((uint4*)gA)[threadIdx.x] = (uint4){0, 0, 0, 0};
    else if (threadIdx.x < 32) ((uint4*)gB)[threadIdx.x - 16] = (uint4){0, 0, 0, 0};
}

// ---------------------------------------------------------------------------
// Ternary-weight prep. L1: f32 natural [co][ci][3][3]; GEMM: bf16 [co][tap][ci]
// ---------------------------------------------------------------------------
__global__ __launch_bounds__(256) void prep_w_l1(
    const void* __restrict__ alpha, const void* __restrict__ betta,
    const int* __restrict__ flags, float* __restrict__ wmv, int n)
{
    int i = blockIdx.x * 256 + threadIdx.x;
    if (i >= n) return;
    int fl = flags[0];
    float a = ldin(alpha, i, fl), b = ldin(betta, i, fl);
    float p0 = 1.f / (1.f + expf(-a));
    float p1 = (1.f - p0) / (1.f + expf(-b));
    float m = 2.f * p1 + p0 - 1.f;
    wmv[i] = m;
    wmv[n + i] = (1.f - p0) - m * m;
}

// thread = OUTPUT index (coalesced writes); scattered reads absorbed by L2.
__global__ __launch_bounds__(256) void prep_w_r(
    const void* __restrict__ alpha, const void* __restrict__ betta,
    const int* __restrict__ flags, bf16* __restrict__ wmr, bf16* __restrict__ wvr,
    int lc, int n)
{
    int o = blockIdx.x * 256 + threadIdx.x;
    if (o >= n) return;
    int fl = flags[0];
    int cotap = o >> lc;            // co*9 + tap
    int ci = o & ((1 << lc) - 1);
    int co = cotap / 9;
    int tap = cotap - co * 9;
    int i = (((co << lc) + ci) * 9) + tap;
    float a = ldin(alpha, i, fl), b = ldin(betta, i, fl);
    float p0 = 1.f / (1.f + expf(-a));
    float p1 = (1.f - p0) / (1.f + expf(-b));
    float m = 2.f * p1 + p0 - 1.f;
    float v = (1.f - p0) - m * m;
    wmr[o] = __float2bfloat16(m);
    wvr[o] = __float2bfloat16(v);
}

// ---------------------------------------------------------------------------
// fc1 weight permute via LDS tile transpose (coalesced both sides)
// ---------------------------------------------------------------------------
__global__ __launch_bounds__(256) void permute_fc1(
    const void* __restrict__ w, const int* __restrict__ flags, bf16* __restrict__ wp)
{
    __shared__ float L[8192];
    const int fl = flags[0];
    int tid = threadIdx.x;
    int o = blockIdx.x;
    size_t srow = (size_t)o * 8192;
    for (int c = tid; c < 512; c += 256) {
        float v[16];
        if (fl) {
            const uint4* s = (const uint4*)((const bf16*)w + srow + c * 16);
            uint4 u0 = s[0], u1 = s[1];
            const unsigned short* h0 = (const unsigned short*)&u0;
            const unsigned short* h1 = (const unsigned short*)&u1;
#pragma unroll
            for (int j = 0; j < 8; j++) { v[j] = b2f_bits((short)h0[j]); v[8 + j] = b2f_bits((short)h1[j]); }
        } else {
            const float4* s = (const float4*)((const float*)w + srow + c * 16);
#pragma unroll
            for (int j = 0; j < 4; j++) {
                float4 t4 = s[j];
                v[j * 4 + 0] = t4.x; v[j * 4 + 1] = t4.y; v[j * 4 + 2] = t4.z; v[j * 4 + 3] = t4.w;
            }
        }
#pragma unroll
        for (int hw = 0; hw < 16; hw++) L[hw * 512 + c] = v[hw];
    }
    __syncthreads();
    for (int j = 0; j < 32; j++) {
        int idx = j * 256 + tid;
        wp[srow + idx] = __float2bfloat16(L[idx]);
    }
}

// ---------------------------------------------------------------------------
// Layer 1 direct conv (CI=3). LDS-staged taps, coalesced NHWC bf16 writes.
// ---------------------------------------------------------------------------
__global__ __launch_bounds__(256) void l1_conv(
    const void* __restrict__ x, const float* __restrict__ wmv,
    const void* __restrict__ bias, const int* __restrict__ flags,
    bf16* __restrict__ out)
{
    __shared__ float Xs[64][28];
    const int fl = flags[0];
    int tid = threadIdx.x;
    int pos0 = blockIdx.x * 64;
    int b = pos0 >> 10;
    for (int u = tid; u < 576; u += 256) {
        int p = u / 9, r = u - p * 9;
        int ci = r / 3, kh = r - ci * 3;
        int pos = pos0 + p;
        int oh = (pos >> 5) & 31, ow = pos & 31;
        int ih = oh - 1 + kh;
        bool okh = (unsigned)ih < 32u;
        size_t base = ((size_t)(b * 3 + ci) * 32 + ih) * 32;
#pragma unroll
        for (int kw = 0; kw < 3; kw++) {
            int iw = ow - 1 + kw;
            float v = (okh && (unsigned)iw < 32u) ? ldin(x, base + iw, fl) : 0.f;
            Xs[p][ci * 9 + kh * 3 + kw] = v;
        }
    }
    int c = tid & 127, pg = tid >> 7;
    float wm[27], wv[27];
#pragma unroll
    for (int k = 0; k < 27; k++) {
        wm[k] = wmv[c * 27 + k];
        wv[k] = wmv[3456 + c * 27 + k];
    }
    float bs = ldin(bias, c, fl);
    __syncthreads();
    for (int it = 0; it < 32; it++) {
        int p = it * 2 + pg;
        float aM = 0.f, aV = 0.f;
#pragma unroll
        for (int k = 0; k < 27; k++) {
            float xv = Xs[p][k];
            aM = fmaf(xv, wm[k], aM);
            aV = fmaf(xv * xv, wv[k], aV);
        }
        out[(size_t)(pos0 + p) * 128 + c] =
            __float2bfloat16(erff((aM + bs) * rsqrtf(2.f * (aV + EPS))));
    }
}

// ---------------------------------------------------------------------------
// Implicit-GEMM LR-conv, bf16 MFMA 16x16x32, NHWC activations.
// Block tile 128pos x 64co, 4 waves, wave tile 64x32 (WJ=2), K-chunk 32.
// Round-6: ZERO VALU in the K-loop.
// - X^2 comes from a producer-written sq region, staged by pure DMA:
//   wave0 -> X, wave1 -> X^2 (same addrs + sqoff), wave2/3 -> Wm/Wv.
//   (R5's in-register sqpk was 112 VALU ops/chunk -> VALUBusy 81.6%,
//   and re-squared every element 9x, once per tap.)
// - Double-buffered (2 x 24KB = 48KB LDS), __launch_bounds__(256,3)
//   -> 3 blocks/CU for TLP overlap of DS/MFMA across blocks.
// - Line-swizzled LDS via pre-permuted global DMA source; frag reads =
//   1 base + imm offsets; conflict-free (verified ~0 since R4).
// - Per chunk: {vmcnt(0) lgkmcnt(0); s_barrier} -> stage(t+1) -> compute(t).
// - SQX=1 (layer 2 only): X/X^2 reg-staged with in-loop sqpk (its producer
//   l1 can't afford a 64MiB sq region); W still DMA.
// - ACT0 epilogue: stage (act, act^2) in LDS, full-line 16B/lane stores.
// ---------------------------------------------------------------------------
template<int CI, int CO, int H, int W, int S, int OH, int OW, int ACT, int SQX, int COT>
__global__ __launch_bounds__(256, 3) void conv_gemm(
    const char* __restrict__ xreg,   // act region: act at +0, sq at +sqoff
    int sqoff, int zpoff,            // zpoff = byte offset of zero guard page
    const bf16* __restrict__ wmr,    // [CO][9][CI]
    const bf16* __restrict__ wvr,
    const void* __restrict__ bias, const void* __restrict__ noise,
    const int* __restrict__ flags,
    void* __restrict__ outp, bf16* __restrict__ outsq)
{
    constexpr int OHW = OH * OW;
    constexpr int KC = CI / 32;      // K-chunks per tap
    constexpr int NC = 9 * KC;       // total K-chunks (even)
    constexpr int WJ = COT / 32;     // b-frags per wave (2)
    constexpr int NW = COT / 16;     // W DMA instrs per stream per chunk (4)
    constexpr int XB = 128 * 64;     // 8KB (128 rows x 64B)
    constexpr int WB = COT * 64;     // 4KB
    constexpr int BUFB = 2 * XB + 2 * WB;   // 24KB
    constexpr int LOHW = ilog2c(OHW), LOW = ilog2c(OW);
    static_assert((NC & 1) == 0 && COT == 64, "");

    __shared__ __align__(16) char smem[2 * BUFB];   // 48KB

    const int tid = threadIdx.x;
    const int lane = tid & 63, wv_ = tid >> 6;
    const int q = lane >> 4, l15 = lane & 15;
    const int pw = (wv_ >> 1) * 64, cw = (wv_ & 1) * (16 * WJ);
    const int c0 = blockIdx.y * COT;
    const int bx128 = blockIdx.x * 128;

    // DMA source permutation (DMA writes LDS linearly; global source is
    // pre-permuted so linear LDS == line-swizzled layout):
    // lane l of instr k: line = 8k+(l>>3), phys slot = l&7
    //  -> logical slot s = (l&7)^(l>>3); row = 16k+2*(l>>3)+(s>>2); unit = s&3
    const int sl   = (lane & 7) ^ (lane >> 3);
    const int row2 = 2 * (lane >> 3) + (sl >> 2);
    const int u16b = (sl & 3) * 16;

    // X per-instr precompute (8 instrs cover the 128-row tile)
    int xb[8], ohS[8], owS[8];
#pragma unroll
    for (int kk = 0; kk < 8; kk++) {
        int P = bx128 + 16 * kk + row2;
        int bi = P >> LOHW;
        ohS[kk] = ((P >> LOW) & (OH - 1)) * S - 1;
        owS[kk] = (P & (OW - 1)) * S - 1;
        xb[kk] = bi * (H * W * CI * 2) + ((!SQX && wv_ == 1) ? sqoff : 0);
    }
    // W stream per-lane base; chunk t's data at +t*64 within [CO][9*CI] rows
    const char* wsb = (const char*)((wv_ == 3) ? wvr : wmr)
                      + (size_t)(c0 + row2) * (9 * CI * 2) + u16b;
    const int wdoff = 2 * XB + ((wv_ == 3) ? WB : 0);
    const int xdoff = (wv_ == 1) ? XB : 0;

    // frag read base (line-swizzle folds to thread-constant + imm offsets)
    const int lA = (l15 >> 1) * 128 + (((((l15 & 1) << 2) | q) ^ (l15 >> 1)) << 4);
    const int abase = pw * 64 + lA;
    const int bbase = cw * 64 + lA;

    f32x4 accM[4][WJ], accV[4][WJ];
#pragma unroll
    for (int i = 0; i < 4; i++)
#pragma unroll
        for (int j = 0; j < WJ; j++) {
            accM[i][j] = (f32x4){0.f, 0.f, 0.f, 0.f};
            accV[i][j] = (f32x4){0.f, 0.f, 0.f, 0.f};
        }

    uint4 g[4];   // SQX reg staging (waves 0/1)

    auto stageX = [&](int t, char* buf) {   // waves 0 (act) / 1 (sq), 8 DMAs
        const int tap = t / KC, kci = (t - tap * KC) * 64;
        const int kh = tap / 3, kw2 = tap - 3 * kh;
#pragma unroll
        for (int kk = 0; kk < 8; kk++) {
            int ih = ohS[kk] + kh, iw = owS[kk] + kw2;
            bool ok = ((unsigned)ih < (unsigned)H) && ((unsigned)iw < (unsigned)W);
            int off = xb[kk] + (ih * W + iw) * (CI * 2) + kci + u16b;
            off = ok ? off : zpoff;
            dma16(xreg + off, buf + xdoff + kk * 1024);
        }
    };
    auto stageW = [&](int t, char* buf) {   // waves 2 (Wm) / 3 (Wv), 4 DMAs
        const char* s = wsb + t * 64;
        char* d = buf + wdoff;
#pragma unroll
        for (int k = 0; k < NW; k++)
            dma16(s + (size_t)k * (16 * 9 * CI * 2), d + k * 1024);
    };
    auto loadX = [&](int t) {               // SQX: waves 0/1 split 8 instrs
        const int tap = t / KC, kci = (t - tap * KC) * 64;
        const int kh = tap / 3, kw2 = tap - 3 * kh;
#pragma unroll
        for (int ts = 0; ts < 4; ts++) {
            const int kk = (wv_ & 1) * 4 + ts;
            int ih = ohS[kk] + kh, iw = owS[kk] + kw2;
            bool ok = ((unsigned)ih < (unsigned)H) && ((unsigned)iw < (unsigned)W);
            int off = xb[kk] + (ih * W + iw) * (CI * 2) + kci + u16b;
            g[ts] = (uint4){0, 0, 0, 0};
            if (ok) g[ts] = *(const uint4*)(xreg + off);
        }
    };
    auto writeX = [&](char* buf) {
#pragma unroll
        for (int ts = 0; ts < 4; ts++) {
            const int kk = (wv_ & 1) * 4 + ts;
            *(uint4*)(buf + kk * 1024 + lane * 16) = g[ts];
            *(uint4*)(buf + XB + kk * 1024 + lane * 16) = sqpk4(g[ts]);
        }
    };

    auto compute = [&](int nb) {
        const char* buf = smem + nb * BUFB;
        s16x8 bm[WJ], bv[WJ];
#pragma unroll
        for (int j = 0; j < WJ; j++) {
            bm[j] = *(const s16x8*)(buf + 2 * XB + bbase + j * 1024);
            bv[j] = *(const s16x8*)(buf + 2 * XB + WB + bbase + j * 1024);
        }
#pragma unroll
        for (int i = 0; i < 4; i++) {
            s16x8 a  = *(const s16x8*)(buf + abase + i * 1024);
            s16x8 aq = *(const s16x8*)(buf + XB + abase + i * 1024);
#pragma unroll
            for (int j = 0; j < WJ; j++) {
                accM[i][j] = __builtin_amdgcn_mfma_f32_16x16x32_bf16(a,  bm[j], accM[i][j], 0, 0, 0);
                accV[i][j] = __builtin_amdgcn_mfma_f32_16x16x32_bf16(aq, bv[j], accV[i][j], 0, 0, 0);
            }
        }
    };

    // wait own chunk DMAs + drain own ds ops, then barrier; single asm block
#define BAR() asm volatile("s_waitcnt vmcnt(0) lgkmcnt(0)\n\ts_barrier" ::: "memory")

    // prologue: chunk 0 into buf 0
    if (wv_ >= 2) stageW(0, smem);
    else if constexpr (!SQX) stageX(0, smem);
    else { loadX(0); writeX(smem); }
    BAR();

    for (int t = 0; t < NC; t += 2) {
        if constexpr (!SQX) {
            if (t + 1 < NC) { if (wv_ < 2) stageX(t + 1, smem + BUFB); else stageW(t + 1, smem + BUFB); }
            compute(0);
        } else {
            if (t + 1 < NC) { if (wv_ >= 2) stageW(t + 1, smem + BUFB); else loadX(t + 1); }
            compute(0);
            if (t + 1 < NC && wv_ < 2) writeX(smem + BUFB);
        }
        BAR();
        if constexpr (!SQX) {
            if (t + 2 < NC) { if (wv_ < 2) stageX(t + 2, smem); else stageW(t + 2, smem); }
            compute(1);
        } else {
            if (t + 2 < NC) { if (wv_ >= 2) stageW(t + 2, smem); else loadX(t + 2); }
            compute(1);
            if (t + 2 < NC && wv_ < 2) writeX(smem);
        }
        BAR();
    }
#undef BAR

    const int fl = flags[0];
    if constexpr (ACT == 0) {
        // LDS-staged epilogue: scatter bf16 act+sq, store full 16B/lane lines
        bf16* Lact = (bf16*)smem;
        bf16* Lsq  = (bf16*)(smem + 128 * COT * 2);
#pragma unroll
        for (int j = 0; j < WJ; j++) {
            int co = c0 + cw + j * 16 + l15;
            float bs = ldin(bias, co, fl);
#pragma unroll
            for (int i = 0; i < 4; i++) {
#pragma unroll
                for (int r = 0; r < 4; r++) {
                    int PPl = pw + i * 16 + q * 4 + r;
                    float mm = accM[i][j][r] + bs, vv = accV[i][j][r];
                    float y = erff(mm * rsqrtf(2.f * (vv + EPS)));
                    bf16 yb = __float2bfloat16(y);
                    float yf = __bfloat162float(yb);
                    int lc = cw + j * 16 + l15;
                    Lact[PPl * COT + lc] = yb;
                    Lsq [PPl * COT + lc] = __float2bfloat16(yf * yf);
                }
            }
        }
        __syncthreads();
        constexpr int LCB = ilog2c(COT * 2);
        constexpr int NST = (128 * COT * 2) / 4096;
#pragma unroll
        for (int k = 0; k < NST; k++) {
            int f = k * 4096 + tid * 16;
            int rowl = f >> LCB;
            int colb = f & ((COT * 2) - 1);
            uint4 va = *(const uint4*)((char*)Lact + f);
            uint4 vs = *(const uint4*)((char*)Lsq + f);
            size_t gb = ((size_t)(bx128 + rowl) * CO + c0) * 2 + colb;
            *(uint4*)((char*)outp + gb) = va;
            *(uint4*)((char*)outsq + gb) = vs;
        }
    } else {
#pragma unroll
        for (int j = 0; j < WJ; j++) {
            int co = c0 + cw + j * 16 + l15;
            float bs = ldin(bias, co, fl);
#pragma unroll
            for (int i = 0; i < 4; i++) {
#pragma unroll
                for (int r = 0; r < 4; r++) {
                    int PP = bx128 + pw + i * 16 + q * 4 + r;
                    float mm = accM[i][j][r] + bs, vv = accV[i][j][r];
                    int bb = PP / OHW, hw = PP % OHW;
                    float nz = ldin(noise, ((size_t)bb * CO + co) * OHW + hw, fl);
                    ((float*)outp)[(size_t)PP * CO + co] = mm + sqrtf(vv + EPS) * nz;
                }
            }
        }
    }
}

// ---------------------------------------------------------------------------
// FC1 split-K MFMA GEMM: partial[ks][256][1024] over K-slice of 512 (x16)
// ---------------------------------------------------------------------------
__global__ __launch_bounds__(256) void fc1_gemm_sk(
    const bf16* __restrict__ A, const bf16* __restrict__ Wp,
    float* __restrict__ part)
{
    __shared__ bf16 Xs[128 * 40];
    __shared__ bf16 Ws[128 * 40];
    int tid = threadIdx.x;
    int lane = tid & 63, wv_ = tid >> 6;
    int q = lane >> 4, l15 = lane & 15;
    const int pw = (wv_ >> 1) * 64, cw = (wv_ & 1) * 64;
    const int p0 = blockIdx.x * 128, c0 = blockIdx.y * 128;
    const int kb = blockIdx.z * 512;
    const int row_i = tid >> 1, half = tid & 1;

    f32x4 acc[4][4];
#pragma unroll
    for (int i = 0; i < 4; i++)
#pragma unroll
        for (int j = 0; j < 4; j++) acc[i][j] = (f32x4){0.f, 0.f, 0.f, 0.f};

    for (int k0 = kb; k0 < kb + 512; k0 += 32) {
        __syncthreads();
        {
            const uint4* s = (const uint4*)(A + (size_t)(p0 + row_i) * 8192 + k0 + half * 16);
            uint4* d = (uint4*)(Xs + row_i * 40 + half * 16);
            d[0] = s[0]; d[1] = s[1];
        }
        {
            const uint4* s = (const uint4*)(Wp + (size_t)(c0 + row_i) * 8192 + k0 + half * 16);
            uint4* d = (uint4*)(Ws + row_i * 40 + half * 16);
            d[0] = s[0]; d[1] = s[1];
        }
        __syncthreads();
        s16x8 a[4], bb[4];
#pragma unroll
        for (int i = 0; i < 4; i++) {
            a[i]  = *(const s16x8*)(Xs + (pw + i * 16 + l15) * 40 + q * 8);
            bb[i] = *(const s16x8*)(Ws + (cw + i * 16 + l15) * 40 + q * 8);
        }
#pragma unroll
        for (int i = 0; i < 4; i++)
#pragma unroll
            for (int j = 0; j < 4; j++)
                acc[i][j] = __builtin_amdgcn_mfma_f32_16x16x32_bf16(a[i], bb[j], acc[i][j], 0, 0, 0);
    }

    float* pbase = part + (size_t)blockIdx.z * 256 * 1024;
#pragma unroll
    for (int j = 0; j < 4; j++) {
        int co = c0 + cw + j * 16 + l15;
#pragma unroll
        for (int i = 0; i < 4; i++) {
            f32x4 m4 = acc[i][j];
#pragma unroll
            for (int r = 0; r < 4; r++) {
                int P = p0 + pw + i * 16 + q * 4 + r;
                pbase[(size_t)P * 1024 + co] = m4[r];
            }
        }
    }
}

__global__ __launch_bounds__(256) void fc1_reduce(
    const float* __restrict__ part, const void* __restrict__ bias,
    const int* __restrict__ flags, float* __restrict__ out)
{
    int i = blockIdx.x * 256 + threadIdx.x;  // 262144
    float s = 0.f;
#pragma unroll
    for (int k = 0; k < 16; k++) s += part[(size_t)k * 262144 + i];
    out[i] = fmaxf(s + ldin(bias, i & 1023, flags[0]), 0.f);
}

// ---------------------------------------------------------------------------
// BatchNorm over NHWC z [4096 pos][512 c]
// ---------------------------------------------------------------------------
__global__ __launch_bounds__(256) void bn_part(const float* __restrict__ z,
                                               float4* __restrict__ partial)
{
    int blk = blockIdx.x;  // 128
    int t = threadIdx.x;
    float s0 = 0, ss0 = 0, s1 = 0, ss1 = 0;
    for (int p = 0; p < 32; p++) {
        float2 v = ((const float2*)z)[((size_t)(blk * 32 + p)) * 256 + t];
        s0 += v.x; ss0 += v.x * v.x;
        s1 += v.y; ss1 += v.y * v.y;
    }
    partial[blk * 256 + t] = make_float4(s0, ss0, s1, ss1);
}

__global__ __launch_bounds__(512) void bn_fin(
    const float4* __restrict__ partial, const void* __restrict__ gamma,
    const void* __restrict__ beta, const int* __restrict__ flags,
    float* __restrict__ sc, float* __restrict__ sh)
{
    int c = threadIdx.x;  // 512
    float s = 0, ss = 0;
    for (int j = 0; j < 128; j++) {
        float4 pv = partial[j * 256 + (c >> 1)];
        s += (c & 1) ? pv.z : pv.x;
        ss += (c & 1) ? pv.w : pv.y;
    }
    float mean = s * (1.f / 4096.f);
    float var = ss * (1.f / 4096.f) - mean * mean;
    int fl = flags[0];
    float scale = ldin(gamma, c, fl) * rsqrtf(var + EPS);
    sc[c] = scale;
    sh[c] = ldin(beta, c, fl) - mean * scale;
}

__global__ __launch_bounds__(256) void bn_apply(
    const float* __restrict__ z, const float* __restrict__ sc,
    const float* __restrict__ sh, bf16* __restrict__ zr)
{
    int i = blockIdx.x * 256 + threadIdx.x;  // 2097152
    int c = i & 511;
    float v = z[i] * sc[c] + sh[c];
    zr[i] = __float2bfloat16(fmaxf(v, 0.f));
}

// ---------------------------------------------------------------------------
// FC2: out[256,10] = fc1o @ W^T + b
// ---------------------------------------------------------------------------
__global__ __launch_bounds__(640) void fc2_kernel(
    const float* __restrict__ A, const void* __restrict__ W,
    const void* __restrict__ bias, const int* __restrict__ flags,
    void* __restrict__ out)
{
    const int fl = flags[0];
    int n = blockIdx.x;
    int o = threadIdx.x >> 6;  // 0..9
    int lane = threadIdx.x & 63;
    const float* a = A + (size_t)n * 1024;
    size_t wbase = (size_t)o * 1024;
    float s = 0.f;
    for (int i = lane; i < 1024; i += 64) s = fmaf(a[i], ldin(W, wbase + i, fl), s);
#pragma unroll
    for (int off = 32; off > 0; off >>= 1) s += __shfl_down(s, off);
    if (lane == 0) {
        float v = s + ldin(bias, o, fl);
        if (fl) ((bf16*)out)[n * 10 + o] = __float2bfloat16(v);
        else    ((float*)out)[n * 10 + o] = v;
    }
}

// ---------------------------------------------------------------------------
extern "C" void kernel_launch(void* const* d_in, const int* in_sizes, int n_in,
                              void* d_out, int out_size, void* d_ws, size_t ws_size,
                              hipStream_t stream)
{
    const void* x = d_in[0];
    const void *al[6], *be[6], *bi[6];
    for (int l = 0; l < 6; l++) {
        al[l] = d_in[1 + 3 * l];
        be[l] = d_in[2 + 3 * l];
        bi[l] = d_in[3 + 3 * l];
    }
    const void* bn_gamma = d_in[19];
    const void* bn_beta  = d_in[20];
    const void* fc1_w = d_in[21];
    const void* fc1_b = d_in[22];
    const void* fc2_w = d_in[23];
    const void* fc2_b = d_in[24];
    const void* noise = d_in[25];

    // ---- workspace (~142 MB, same as the passing R2 layout) ----
    char* base = (char*)d_ws;
    size_t off = 0;
    auto alloc = [&](size_t bytes) { void* p = base + off; off += (bytes + 255) & ~(size_t)255; return p; };
    int* flags = (int*)alloc(256);
    float* w1 = (float*)alloc(2 * 3456 * sizeof(float));
    const int SwLC[5] = {7, 7, 8, 8, 9};        // log2(CI)
    const size_t Sw[5] = {147456, 294912, 589824, 1179648, 2359296};
    bf16 *wmr[5], *wvr[5];
    for (int l = 0; l < 5; l++) {
        wmr[l] = (bf16*)alloc(Sw[l] * sizeof(bf16));
        wvr[l] = (bf16*)alloc(Sw[l] * sizeof(bf16));
    }
    bf16* Wp   = (bf16*)alloc((size_t)1024 * 8192 * sizeof(bf16));       // 16.8 MB
    float4* part = (float4*)alloc((size_t)128 * 256 * sizeof(float4));   // 0.5 MB
    float* bnsc = (float*)alloc(512 * sizeof(float));
    float* bnsh = (float*)alloc(512 * sizeof(float));
    float* fc1o = (float*)alloc((size_t)256 * 1024 * sizeof(float));     // 1 MB
    bf16* zr   = (bf16*)alloc((size_t)256 * 8192 * sizeof(bf16));        // 4.2 MB

    // activation regions (act + sq pairs) + 256B zero guard pages
    const int ZPA = 67108864;   // RA: L1 act (64Mi) | L3 act+sq | L5 act+sq
    const int ZPB = 33554432;   // RB: L2 act+sq | L4 act+sq | z + fc1part
    char* RA = (char*)alloc((size_t)ZPA + 256);
    char* RB = (char*)alloc((size_t)ZPB + 256);
    float* z = (float*)RB;                           // L6 out, 8.4 MB f32
    float* fc1part = (float*)(RB + 8388608);         // 16.8 MB f32 (L4 dead)

    detect_kernel<<<1, 64, 0, stream>>>(x, flags, RA + ZPA, RB + ZPB);

    prep_w_l1<<<14, 256, 0, stream>>>(al[0], be[0], flags, w1, 3456);
    for (int l = 0; l < 5; l++) {
        int n = (int)Sw[l];
        prep_w_r<<<(n + 255) / 256, 256, 0, stream>>>(
            al[l + 1], be[l + 1], flags, wmr[l], wvr[l], SwLC[l], n);
    }
    permute_fc1<<<1024, 256, 0, stream>>>(fc1_w, flags, Wp);

    // layer 1: direct, NHWC bf16 out, coalesced
    l1_conv<<<4096, 256, 0, stream>>>(x, w1, bi[0], flags, (bf16*)RA);

    // layers 2..6: implicit-GEMM MFMA, DMA-staged X/X^2/Wm/Wv, double-buffer,
    // 3 blocks/CU, zero loop-VALU (L2 = SQX reg path). Epilogues emit act+sq.
    conv_gemm<128, 128, 32, 32, 2, 16, 16, 0, 1, 64><<<dim3(512, 2), 256, 0, stream>>>(
        RA, 0, ZPA, wmr[0], wvr[0], bi[1], nullptr, flags,
        RB, (bf16*)(RB + 16777216));
    conv_gemm<128, 256, 16, 16, 1, 16, 16, 0, 0, 64><<<dim3(512, 4), 256, 0, stream>>>(
        RB, 16777216, ZPB, wmr[1], wvr[1], bi[2], nullptr, flags,
        RA, (bf16*)(RA + 33554432));
    conv_gemm<256, 256, 16, 16, 2, 8, 8, 0, 0, 64><<<dim3(128, 4), 256, 0, stream>>>(
        RA, 33554432, ZPA, wmr[2], wvr[2], bi[3], nullptr, flags,
        RB, (bf16*)(RB + 8388608));
    conv_gemm<256, 512, 8, 8, 1, 8, 8, 0, 0, 64><<<dim3(128, 8), 256, 0, stream>>>(
        RB, 8388608, ZPB, wmr[3], wvr[3], bi[4], nullptr, flags,
        RA, (bf16*)(RA + 16777216));
    conv_gemm<512, 512, 8, 8, 2, 4, 4, 1, 0, 64><<<dim3(32, 8), 256, 0, stream>>>(
        RA, 16777216, ZPA, wmr[4], wvr[4], bi[5], noise, flags,
        z, nullptr);

    // batchnorm + relu (NHWC == fc1 k' order)
    bn_part<<<128, 256, 0, stream>>>(z, part);
    bn_fin<<<1, 512, 0, stream>>>(part, bn_gamma, bn_beta, flags, bnsc, bnsh);
    bn_apply<<<8192, 256, 0, stream>>>(z, bnsc, bnsh, zr);

    // classifier head (split-K x16 into fc1part, then reduce+bias+relu)
    fc1_gemm_sk<<<dim3(2, 8, 16), 256, 0, stream>>>(zr, Wp, fc1part);
    fc1_reduce<<<1024, 256, 0, stream>>>(fc1part, fc1_b, flags, fc1o);
    fc2_kernel<<<256, 640, 0, stream>>>(fc1o, fc2_w, fc2_b, flags, d_out);
}

// Round 7
// 709.130 us; speedup vs baseline: 1.1482x; 1.1482x over previous
//
#include <hip/hip_runtime.h>
#include <hip/hip_bf16.h>
#include <math.h>

#define EPS 1e-5f

typedef __hip_bfloat16 bf16;
typedef short s16x8 __attribute__((ext_vector_type(8)));
typedef float f32x4 __attribute__((ext_vector_type(4)));

constexpr int ilog2c(int v) { return v <= 1 ? 0 : 1 + ilog2c(v >> 1); }

__device__ __forceinline__ float ldin(const void* p, size_t i, int isbf) {
    return isbf ? __bfloat162float(((const bf16*)p)[i]) : ((const float*)p)[i];
}
__device__ __forceinline__ float b2f_bits(short s) {
    unsigned u = ((unsigned)(unsigned short)s) << 16;
    return __builtin_bit_cast(float, u);
}
// packed square of 2 bf16 in one dword, round-half-up (x^2 >= 0)
__device__ __forceinline__ unsigned sqpk1(unsigned w) {
    float lo = __builtin_bit_cast(float, w << 16);
    float hi = __builtin_bit_cast(float, w & 0xffff0000u);
    lo *= lo; hi *= hi;
    unsigned ul = __builtin_bit_cast(unsigned, lo) + 0x8000u;
    unsigned uh = __builtin_bit_cast(unsigned, hi) + 0x8000u;
    return __builtin_amdgcn_perm(uh, ul, 0x07060302);  // [uh.b3 uh.b2 ul.b3 ul.b2]
}
__device__ __forceinline__ uint4 sqpk4(uint4 u) {
    uint4 r;
    r.x = sqpk1(u.x); r.y = sqpk1(u.y); r.z = sqpk1(u.z); r.w = sqpk1(u.w);
    return r;
}

// async global->LDS DMA, 16B/lane; LDS dest = wave-uniform base + lane*16
__device__ __forceinline__ void dma16(const void* g, void* l) {
    __builtin_amdgcn_global_load_lds(
        (const __attribute__((address_space(1))) void*)g,
        (__attribute__((address_space(3))) void*)l, 16, 0, 0);
}

// ---------------------------------------------------------------------------
// dtype sniff (f32 vs bf16-packed inputs); flags[0]=1 => bf16
// also zeroes the OOB guard pages of the two activation regions
// ---------------------------------------------------------------------------
__global__ __launch_bounds__(64) void detect_kernel(const void* __restrict__ x,
                                                    int* __restrict__ flags,
                                                    char* __restrict__ gA,
                                                    char* __restrict__ gB) {
    const unsigned* w = (const unsigned*)x;
    unsigned word = w[threadIdx.x];
    int e = (word >> 23) & 0xFF;
    bool ok = (word == 0u) || (e >= 0x70 && e <= 0x8E);
    unsigned long long m = __ballot(ok);
    if (threadIdx.x == 0) flags[0] = (__popcll(m) >= 32) ? 0 : 1;
    if (threadIdx.x < 16) ((uint4*)gA)[threadIdx.x] = (uint4){0, 0, 0, 0};
    else if (threadIdx.x < 32) ((uint4*)gB)[threadIdx.x - 16] = (uint4){0, 0, 0, 0};
}

// ---------------------------------------------------------------------------
// Ternary-weight prep. L1: f32 natural [co][ci][3][3]; GEMM: bf16 [co][tap][ci]
// ---------------------------------------------------------------------------
__global__ __launch_bounds__(256) void prep_w_l1(
    const void* __restrict__ alpha, const void* __restrict__ betta,
    const int* __restrict__ flags, float* __restrict__ wmv, int n)
{
    int i = blockIdx.x * 256 + threadIdx.x;
    if (i >= n) return;
    int fl = flags[0];
    float a = ldin(alpha, i, fl), b = ldin(betta, i, fl);
    float p0 = 1.f / (1.f + expf(-a));
    float p1 = (1.f - p0) / (1.f + expf(-b));
    float m = 2.f * p1 + p0 - 1.f;
    wmv[i] = m;
    wmv[n + i] = (1.f - p0) - m * m;
}

// thread = OUTPUT index (coalesced writes); scattered reads absorbed by L2.
__global__ __launch_bounds__(256) void prep_w_r(
    const void* __restrict__ alpha, const void* __restrict__ betta,
    const int* __restrict__ flags, bf16* __restrict__ wmr, bf16* __restrict__ wvr,
    int lc, int n)
{
    int o = blockIdx.x * 256 + threadIdx.x;
    if (o >= n) return;
    int fl = flags[0];
    int cotap = o >> lc;            // co*9 + tap
    int ci = o & ((1 << lc) - 1);
    int co = cotap / 9;
    int tap = cotap - co * 9;
    int i = (((co << lc) + ci) * 9) + tap;
    float a = ldin(alpha, i, fl), b = ldin(betta, i, fl);
    float p0 = 1.f / (1.f + expf(-a));
    float p1 = (1.f - p0) / (1.f + expf(-b));
    float m = 2.f * p1 + p0 - 1.f;
    float v = (1.f - p0) - m * m;
    wmr[o] = __float2bfloat16(m);
    wvr[o] = __float2bfloat16(v);
}

// ---------------------------------------------------------------------------
// fc1 weight permute via LDS tile transpose (coalesced both sides)
// ---------------------------------------------------------------------------
__global__ __launch_bounds__(256) void permute_fc1(
    const void* __restrict__ w, const int* __restrict__ flags, bf16* __restrict__ wp)
{
    __shared__ float L[8192];
    const int fl = flags[0];
    int tid = threadIdx.x;
    int o = blockIdx.x;
    size_t srow = (size_t)o * 8192;
    for (int c = tid; c < 512; c += 256) {
        float v[16];
        if (fl) {
            const uint4* s = (const uint4*)((const bf16*)w + srow + c * 16);
            uint4 u0 = s[0], u1 = s[1];
            const unsigned short* h0 = (const unsigned short*)&u0;
            const unsigned short* h1 = (const unsigned short*)&u1;
#pragma unroll
            for (int j = 0; j < 8; j++) { v[j] = b2f_bits((short)h0[j]); v[8 + j] = b2f_bits((short)h1[j]); }
        } else {
            const float4* s = (const float4*)((const float*)w + srow + c * 16);
#pragma unroll
            for (int j = 0; j < 4; j++) {
                float4 t4 = s[j];
                v[j * 4 + 0] = t4.x; v[j * 4 + 1] = t4.y; v[j * 4 + 2] = t4.z; v[j * 4 + 3] = t4.w;
            }
        }
#pragma unroll
        for (int hw = 0; hw < 16; hw++) L[hw * 512 + c] = v[hw];
    }
    __syncthreads();
    for (int j = 0; j < 32; j++) {
        int idx = j * 256 + tid;
        wp[srow + idx] = __float2bfloat16(L[idx]);
    }
}

// ---------------------------------------------------------------------------
// Layer 1 direct conv (CI=3). LDS-staged taps, coalesced NHWC bf16 writes.
// ---------------------------------------------------------------------------
__global__ __launch_bounds__(256) void l1_conv(
    const void* __restrict__ x, const float* __restrict__ wmv,
    const void* __restrict__ bias, const int* __restrict__ flags,
    bf16* __restrict__ out)
{
    __shared__ float Xs[64][28];
    const int fl = flags[0];
    int tid = threadIdx.x;
    int pos0 = blockIdx.x * 64;
    int b = pos0 >> 10;
    for (int u = tid; u < 576; u += 256) {
        int p = u / 9, r = u - p * 9;
        int ci = r / 3, kh = r - ci * 3;
        int pos = pos0 + p;
        int oh = (pos >> 5) & 31, ow = pos & 31;
        int ih = oh - 1 + kh;
        bool okh = (unsigned)ih < 32u;
        size_t base = ((size_t)(b * 3 + ci) * 32 + ih) * 32;
#pragma unroll
        for (int kw = 0; kw < 3; kw++) {
            int iw = ow - 1 + kw;
            float v = (okh && (unsigned)iw < 32u) ? ldin(x, base + iw, fl) : 0.f;
            Xs[p][ci * 9 + kh * 3 + kw] = v;
        }
    }
    int c = tid & 127, pg = tid >> 7;
    float wm[27], wv[27];
#pragma unroll
    for (int k = 0; k < 27; k++) {
        wm[k] = wmv[c * 27 + k];
        wv[k] = wmv[3456 + c * 27 + k];
    }
    float bs = ldin(bias, c, fl);
    __syncthreads();
    for (int it = 0; it < 32; it++) {
        int p = it * 2 + pg;
        float aM = 0.f, aV = 0.f;
#pragma unroll
        for (int k = 0; k < 27; k++) {
            float xv = Xs[p][k];
            aM = fmaf(xv, wm[k], aM);
            aV = fmaf(xv * xv, wv[k], aV);
        }
        out[(size_t)(pos0 + p) * 128 + c] =
            __float2bfloat16(erff((aM + bs) * rsqrtf(2.f * (aV + EPS))));
    }
}

// ---------------------------------------------------------------------------
// Implicit-GEMM LR-conv, bf16 MFMA 16x16x32, NHWC activations.
// Block tile 128pos x 64co, 4 waves, K-chunk 32.
// Round-7: wave tile 32pos x 64co (acc[2][4]) — halves the in-register
// squaring cost per MFMA (2 a-frags feed 16 MFMAs; each X element squared
// once per tap, not twice). R5's 64x32 tile had VALU:MFMA demand ~3:1
// (VALUBusy 81.6 / MfmaUtil 29); this layout gives ~1.5:1.
// (R6's DMA-staged producer-side X^2 lost L3 residency: FETCH 14.5->130 MB.
//  Act-only X regions + in-register squares are empirically mandatory.)
// - Double-buffered DMA (2 x 16KB = 32KB LDS), __launch_bounds__(256,3)
//   -> 3 blocks/CU, VGPR cap 168 (acc 64 + frags ~24 + addr fits).
// - Line-swizzled LDS via pre-permuted global DMA source; frag reads =
//   1 base + imm offsets; conflict-free (verified ~0 since R4).
// - Per chunk: {vmcnt(0) lgkmcnt(0); s_barrier} -> stage(t+1) -> compute(t).
// - OOB taps -> zero guard page redirect. LDS-staged coalesced epilogue.
// ---------------------------------------------------------------------------
template<int CI, int CO, int H, int W, int S, int OH, int OW, int ACT, int COT>
__global__ __launch_bounds__(256, 3) void conv_gemm(
    const char* __restrict__ xreg,   // NHWC act region (bf16)
    int zpoff,                       // byte offset of zero guard page
    const bf16* __restrict__ wmr,    // [CO][9][CI]
    const bf16* __restrict__ wvr,
    const void* __restrict__ bias, const void* __restrict__ noise,
    const int* __restrict__ flags, void* __restrict__ outp)
{
    constexpr int OHW = OH * OW;
    constexpr int KC = CI / 32;      // K-chunks per tap
    constexpr int NC = 9 * KC;       // total K-chunks (even: KC is even)
    constexpr int NW = COT / 16;     // W DMA instrs per stream per chunk (4)
    constexpr int XB = 128 * 64;     // 8KB  (128 rows x 64B)
    constexpr int WB = COT * 64;     // 4KB
    constexpr int BUFB = XB + 2 * WB;   // 16KB
    constexpr int LOHW = ilog2c(OHW), LOW = ilog2c(OW);
    static_assert((NC & 1) == 0 && COT == 64, "");

    __shared__ __align__(16) char smem[2 * BUFB];

    const int tid = threadIdx.x;
    const int lane = tid & 63, wv_ = tid >> 6;
    const int q = lane >> 4, l15 = lane & 15;
    const int pw = wv_ * 32;         // wave owns 32 positions, all 64 cos
    const int c0 = blockIdx.y * COT;
    const int bx128 = blockIdx.x * 128;

    // DMA source permutation: DMA writes LDS linearly; global source is
    // pre-permuted so linear LDS == line-swizzled layout.
    // lane l of instr k: line = 8k+(l>>3), phys slot = l&7
    //   -> logical slot s = (l&7)^(l>>3); row = 16k + 2*(l>>3) + (s>>2); unit = s&3
    const int sl   = (lane & 7) ^ (lane >> 3);
    const int row2 = 2 * (lane >> 3) + (sl >> 2);
    const int u16b = (sl & 3) * 16;

    // X per-instr precompute (waves 0/1; wave w covers instrs 4w..4w+3)
    int xb[4], ohS[4], owS[4];
#pragma unroll
    for (int kk = 0; kk < 4; kk++) {
        int P = bx128 + 16 * ((wv_ & 1) * 4 + kk) + row2;
        int bi = P >> LOHW;
        ohS[kk] = ((P >> LOW) & (OH - 1)) * S - 1;
        owS[kk] = (P & (OW - 1)) * S - 1;
        xb[kk] = bi * (H * W * CI * 2);
    }
    // W stream per-lane base; chunk t's data at +t*64 within [CO][9*CI] rows
    const char* wsb = (const char*)((wv_ == 3) ? wvr : wmr)
                      + (size_t)(c0 + row2) * (9 * CI * 2) + u16b;
    const int wdoff = XB + ((wv_ == 3) ? WB : 0);

    // frag read base (line-swizzle folds to thread-constant + imm offsets)
    const int lA = (l15 >> 1) * 128 + (((((l15 & 1) << 2) | q) ^ (l15 >> 1)) << 4);
    const int abase = pw * 64 + lA;
    const int bbase = lA;            // b rows start at co 0 (cw = 0)

    f32x4 accM[2][4], accV[2][4];
#pragma unroll
    for (int i = 0; i < 2; i++)
#pragma unroll
        for (int j = 0; j < 4; j++) {
            accM[i][j] = (f32x4){0.f, 0.f, 0.f, 0.f};
            accV[i][j] = (f32x4){0.f, 0.f, 0.f, 0.f};
        }

    auto stage = [&](int t, int nb) {
        char* buf = smem + nb * BUFB;
        if (wv_ < 2) {
            const int tap = t / KC, kci = (t - tap * KC) * 64;
            const int kh = tap / 3, kw2 = tap - 3 * kh;
#pragma unroll
            for (int kk = 0; kk < 4; kk++) {
                int ih = ohS[kk] + kh, iw = owS[kk] + kw2;
                bool ok = ((unsigned)ih < (unsigned)H) && ((unsigned)iw < (unsigned)W);
                int off = xb[kk] + (ih * W + iw) * (CI * 2) + kci + u16b;
                off = ok ? off : zpoff;
                dma16(xreg + off, buf + ((wv_ & 1) * 4 + kk) * 1024);
            }
        } else {
            const char* s = wsb + t * 64;
            char* d = buf + wdoff;
#pragma unroll
            for (int k = 0; k < NW; k++)
                dma16(s + (size_t)k * (16 * 9 * CI * 2), d + k * 1024);
        }
    };

    auto compute = [&](int nb) {
        const char* buf = smem + nb * BUFB;
        s16x8 a[2], aq[2];
#pragma unroll
        for (int i = 0; i < 2; i++) {
            a[i] = *(const s16x8*)(buf + abase + i * 1024);
            uint4 uq = sqpk4(*(const uint4*)&a[i]);
            aq[i] = *(const s16x8*)&uq;
        }
#pragma unroll
        for (int j = 0; j < 4; j++) {
            s16x8 bm = *(const s16x8*)(buf + XB + bbase + j * 1024);
            s16x8 bv = *(const s16x8*)(buf + XB + WB + bbase + j * 1024);
#pragma unroll
            for (int i = 0; i < 2; i++) {
                accM[i][j] = __builtin_amdgcn_mfma_f32_16x16x32_bf16(a[i],  bm, accM[i][j], 0, 0, 0);
                accV[i][j] = __builtin_amdgcn_mfma_f32_16x16x32_bf16(aq[i], bv, accV[i][j], 0, 0, 0);
            }
        }
    };

    // wait own chunk-t DMAs (only outstanding VM ops) + drain own ds_reads of
    // t-1 (so overwriting buf t-1 is safe after the barrier), then barrier.
#define BAR() asm volatile("s_waitcnt vmcnt(0) lgkmcnt(0)\n\ts_barrier" ::: "memory")

    stage(0, 0);
    for (int t = 0; t < NC; t += 2) {
        BAR();
        if (t + 1 < NC) stage(t + 1, 1);
        compute(0);
        BAR();
        if (t + 2 < NC) stage(t + 2, 0);
        compute(1);
    }
#undef BAR

    __syncthreads();
    const int fl = flags[0];
    if constexpr (ACT == 0) {
        // LDS-staged epilogue: scatter bf16 tile, store full-line 16B/lane
        bf16* Lact = (bf16*)smem;
        constexpr int LCB = ilog2c(COT * 2);
#pragma unroll
        for (int j = 0; j < 4; j++) {
            int co = c0 + j * 16 + l15;
            float bs = ldin(bias, co, fl);
#pragma unroll
            for (int i = 0; i < 2; i++) {
#pragma unroll
                for (int r = 0; r < 4; r++) {
                    int PPl = pw + i * 16 + q * 4 + r;
                    float mm = accM[i][j][r] + bs, vv = accV[i][j][r];
                    Lact[PPl * COT + j * 16 + l15] =
                        __float2bfloat16(erff(mm * rsqrtf(2.f * (vv + EPS))));
                }
            }
        }
        __syncthreads();
        constexpr int NST = (128 * COT * 2) / 4096;
#pragma unroll
        for (int k = 0; k < NST; k++) {
            int f = k * 4096 + tid * 16;
            int rowl = f >> LCB;
            int colb = f & ((COT * 2) - 1);
            uint4 va = *(const uint4*)((char*)smem + f);
            size_t gb = ((size_t)(bx128 + rowl) * CO + c0) * 2 + colb;
            *(uint4*)((char*)outp + gb) = va;
        }
    } else {
#pragma unroll
        for (int j = 0; j < 4; j++) {
            int co = c0 + j * 16 + l15;
            float bs = ldin(bias, co, fl);
#pragma unroll
            for (int i = 0; i < 2; i++) {
#pragma unroll
                for (int r = 0; r < 4; r++) {
                    int PP = bx128 + pw + i * 16 + q * 4 + r;
                    float mm = accM[i][j][r] + bs, vv = accV[i][j][r];
                    int bb = PP / OHW, hw = PP % OHW;
                    float nz = ldin(noise, ((size_t)bb * CO + co) * OHW + hw, fl);
                    ((float*)outp)[(size_t)PP * CO + co] = mm + sqrtf(vv + EPS) * nz;
                }
            }
        }
    }
}

// ---------------------------------------------------------------------------
// FC1 split-K MFMA GEMM: partial[ks][256][1024] over K-slice of 1024
// ---------------------------------------------------------------------------
__global__ __launch_bounds__(256) void fc1_gemm_sk(
    const bf16* __restrict__ A, const bf16* __restrict__ Wp,
    float* __restrict__ part)
{
    __shared__ bf16 Xs[128 * 40];
    __shared__ bf16 Ws[128 * 40];
    int tid = threadIdx.x;
    int lane = tid & 63, wv_ = tid >> 6;
    int q = lane >> 4, l15 = lane & 15;
    const int pw = (wv_ >> 1) * 64, cw = (wv_ & 1) * 64;
    const int p0 = blockIdx.x * 128, c0 = blockIdx.y * 128;
    const int kb = blockIdx.z * 1024;
    const int row_i = tid >> 1, half = tid & 1;

    f32x4 acc[4][4];
#pragma unroll
    for (int i = 0; i < 4; i++)
#pragma unroll
        for (int j = 0; j < 4; j++) acc[i][j] = (f32x4){0.f, 0.f, 0.f, 0.f};

    for (int k0 = kb; k0 < kb + 1024; k0 += 32) {
        __syncthreads();
        {
            const uint4* s = (const uint4*)(A + (size_t)(p0 + row_i) * 8192 + k0 + half * 16);
            uint4* d = (uint4*)(Xs + row_i * 40 + half * 16);
            d[0] = s[0]; d[1] = s[1];
        }
        {
            const uint4* s = (const uint4*)(Wp + (size_t)(c0 + row_i) * 8192 + k0 + half * 16);
            uint4* d = (uint4*)(Ws + row_i * 40 + half * 16);
            d[0] = s[0]; d[1] = s[1];
        }
        __syncthreads();
        s16x8 a[4], bb[4];
#pragma unroll
        for (int i = 0; i < 4; i++) {
            a[i]  = *(const s16x8*)(Xs + (pw + i * 16 + l15) * 40 + q * 8);
            bb[i] = *(const s16x8*)(Ws + (cw + i * 16 + l15) * 40 + q * 8);
        }
#pragma unroll
        for (int i = 0; i < 4; i++)
#pragma unroll
            for (int j = 0; j < 4; j++)
                acc[i][j] = __builtin_amdgcn_mfma_f32_16x16x32_bf16(a[i], bb[j], acc[i][j], 0, 0, 0);
    }

    float* pbase = part + (size_t)blockIdx.z * 256 * 1024;
#pragma unroll
    for (int j = 0; j < 4; j++) {
        int co = c0 + cw + j * 16 + l15;
#pragma unroll
        for (int i = 0; i < 4; i++) {
            f32x4 m4 = acc[i][j];
#pragma unroll
            for (int r = 0; r < 4; r++) {
                int P = p0 + pw + i * 16 + q * 4 + r;
                pbase[(size_t)P * 1024 + co] = m4[r];
            }
        }
    }
}

__global__ __launch_bounds__(256) void fc1_reduce(
    const float* __restrict__ part, const void* __restrict__ bias,
    const int* __restrict__ flags, float* __restrict__ out)
{
    int i = blockIdx.x * 256 + threadIdx.x;  // 262144
    float s = 0.f;
#pragma unroll
    for (int k = 0; k < 8; k++) s += part[(size_t)k * 262144 + i];
    out[i] = fmaxf(s + ldin(bias, i & 1023, flags[0]), 0.f);
}

// ---------------------------------------------------------------------------
// BatchNorm over NHWC z [4096 pos][512 c]
// ---------------------------------------------------------------------------
__global__ __launch_bounds__(256) void bn_part(const float* __restrict__ z,
                                               float4* __restrict__ partial)
{
    int blk = blockIdx.x;  // 128
    int t = threadIdx.x;
    float s0 = 0, ss0 = 0, s1 = 0, ss1 = 0;
    for (int p = 0; p < 32; p++) {
        float2 v = ((const float2*)z)[((size_t)(blk * 32 + p)) * 256 + t];
        s0 += v.x; ss0 += v.x * v.x;
        s1 += v.y; ss1 += v.y * v.y;
    }
    partial[blk * 256 + t] = make_float4(s0, ss0, s1, ss1);
}

__global__ __launch_bounds__(512) void bn_fin(
    const float4* __restrict__ partial, const void* __restrict__ gamma,
    const void* __restrict__ beta, const int* __restrict__ flags,
    float* __restrict__ sc, float* __restrict__ sh)
{
    int c = threadIdx.x;  // 512
    float s = 0, ss = 0;
    for (int j = 0; j < 128; j++) {
        float4 pv = partial[j * 256 + (c >> 1)];
        s += (c & 1) ? pv.z : pv.x;
        ss += (c & 1) ? pv.w : pv.y;
    }
    float mean = s * (1.f / 4096.f);
    float var = ss * (1.f / 4096.f) - mean * mean;
    int fl = flags[0];
    float scale = ldin(gamma, c, fl) * rsqrtf(var + EPS);
    sc[c] = scale;
    sh[c] = ldin(beta, c, fl) - mean * scale;
}

__global__ __launch_bounds__(256) void bn_apply(
    const float* __restrict__ z, const float* __restrict__ sc,
    const float* __restrict__ sh, bf16* __restrict__ zr)
{
    int i = blockIdx.x * 256 + threadIdx.x;  // 2097152
    int c = i & 511;
    float v = z[i] * sc[c] + sh[c];
    zr[i] = __float2bfloat16(fmaxf(v, 0.f));
}

// ---------------------------------------------------------------------------
// FC2: out[256,10] = fc1o @ W^T + b
// ---------------------------------------------------------------------------
__global__ __launch_bounds__(640) void fc2_kernel(
    const float* __restrict__ A, const void* __restrict__ W,
    const void* __restrict__ bias, const int* __restrict__ flags,
    void* __restrict__ out)
{
    const int fl = flags[0];
    int n = blockIdx.x;
    int o = threadIdx.x >> 6;  // 0..9
    int lane = threadIdx.x & 63;
    const float* a = A + (size_t)n * 1024;
    size_t wbase = (size_t)o * 1024;
    float s = 0.f;
    for (int i = lane; i < 1024; i += 64) s = fmaf(a[i], ldin(W, wbase + i, fl), s);
#pragma unroll
    for (int off = 32; off > 0; off >>= 1) s += __shfl_down(s, off);
    if (lane == 0) {
        float v = s + ldin(bias, o, fl);
        if (fl) ((bf16*)out)[n * 10 + o] = __float2bfloat16(v);
        else    ((float*)out)[n * 10 + o] = v;
    }
}

// ---------------------------------------------------------------------------
extern "C" void kernel_launch(void* const* d_in, const int* in_sizes, int n_in,
                              void* d_out, int out_size, void* d_ws, size_t ws_size,
                              hipStream_t stream)
{
    const void* x = d_in[0];
    const void *al[6], *be[6], *bi[6];
    for (int l = 0; l < 6; l++) {
        al[l] = d_in[1 + 3 * l];
        be[l] = d_in[2 + 3 * l];
        bi[l] = d_in[3 + 3 * l];
    }
    const void* bn_gamma = d_in[19];
    const void* bn_beta  = d_in[20];
    const void* fc1_w = d_in[21];
    const void* fc1_b = d_in[22];
    const void* fc2_w = d_in[23];
    const void* fc2_b = d_in[24];
    const void* noise = d_in[25];

    // ---- workspace (~125 MB) ----
    char* base = (char*)d_ws;
    size_t off = 0;
    auto alloc = [&](size_t bytes) { void* p = base + off; off += (bytes + 255) & ~(size_t)255; return p; };
    int* flags = (int*)alloc(256);
    float* w1 = (float*)alloc(2 * 3456 * sizeof(float));
    const int SwLC[5] = {7, 7, 8, 8, 9};        // log2(CI)
    const size_t Sw[5] = {147456, 294912, 589824, 1179648, 2359296};
    bf16 *wmr[5], *wvr[5];
    for (int l = 0; l < 5; l++) {
        wmr[l] = (bf16*)alloc(Sw[l] * sizeof(bf16));
        wvr[l] = (bf16*)alloc(Sw[l] * sizeof(bf16));
    }
    bf16* Wp   = (bf16*)alloc((size_t)1024 * 8192 * sizeof(bf16));       // 16.8 MB
    float4* part = (float4*)alloc((size_t)128 * 256 * sizeof(float4));   // 0.5 MB
    float* bnsc = (float*)alloc(512 * sizeof(float));
    float* bnsh = (float*)alloc(512 * sizeof(float));
    float* fc1o = (float*)alloc((size_t)256 * 1024 * sizeof(float));     // 1 MB
    bf16* zr   = (bf16*)alloc((size_t)256 * 8192 * sizeof(bf16));        // 4.2 MB

    // activation regions (act only) + 256B zero guard pages
    const int ZPA = 67108864;   // RA interior: L1 act (64 MiB) | L3 act | L5 act
    const int ZPB = 16777216;   // RB interior: L2 act | L4 act | z+fc1part
    char* RA = (char*)alloc((size_t)ZPA + 256);
    char* RB = (char*)alloc((size_t)ZPB + 256);
    float* z = (float*)RB;                           // L6 out, 8.4 MB f32
    float* fc1part = (float*)(RB + 8388608);         // 8.4 MB f32 (L4 dead)

    detect_kernel<<<1, 64, 0, stream>>>(x, flags, RA + ZPA, RB + ZPB);

    prep_w_l1<<<14, 256, 0, stream>>>(al[0], be[0], flags, w1, 3456);
    for (int l = 0; l < 5; l++) {
        int n = (int)Sw[l];
        prep_w_r<<<(n + 255) / 256, 256, 0, stream>>>(
            al[l + 1], be[l + 1], flags, wmr[l], wvr[l], SwLC[l], n);
    }
    permute_fc1<<<1024, 256, 0, stream>>>(fc1_w, flags, Wp);

    // layer 1: direct, NHWC bf16 out, coalesced
    l1_conv<<<4096, 256, 0, stream>>>(x, w1, bi[0], flags, (bf16*)RA);

    // layers 2..6: implicit-GEMM MFMA, 128x64 tiles, 32posx64co wave tiles,
    // double-buffered DMA, 3 blocks/CU, in-register X^2 (once per element)
    conv_gemm<128, 128, 32, 32, 2, 16, 16, 0, 64><<<dim3(512, 2), 256, 0, stream>>>(
        RA, ZPA, wmr[0], wvr[0], bi[1], nullptr, flags, RB);
    conv_gemm<128, 256, 16, 16, 1, 16, 16, 0, 64><<<dim3(512, 4), 256, 0, stream>>>(
        RB, ZPB, wmr[1], wvr[1], bi[2], nullptr, flags, RA);
    conv_gemm<256, 256, 16, 16, 2, 8, 8, 0, 64><<<dim3(128, 4), 256, 0, stream>>>(
        RA, ZPA, wmr[2], wvr[2], bi[3], nullptr, flags, RB);
    conv_gemm<256, 512, 8, 8, 1, 8, 8, 0, 64><<<dim3(128, 8), 256, 0, stream>>>(
        RB, ZPB, wmr[3], wvr[3], bi[4], nullptr, flags, RA);
    conv_gemm<512, 512, 8, 8, 2, 4, 4, 1, 64><<<dim3(32, 8), 256, 0, stream>>>(
        RA, ZPA, wmr[4], wvr[4], bi[5], noise, flags, z);

    // batchnorm + relu (NHWC == fc1 k' order)
    bn_part<<<128, 256, 0, stream>>>(z, part);
    bn_fin<<<1, 512, 0, stream>>>(part, bn_gamma, bn_beta, flags, bnsc, bnsh);
    bn_apply<<<8192, 256, 0, stream>>>(z, bnsc, bnsh, zr);

    // classifier head (split-K x8 into fc1part, then reduce+bias+relu)
    fc1_gemm_sk<<<dim3(2, 8, 8), 256, 0, stream>>>(zr, Wp, fc1part);
    fc1_reduce<<<1024, 256, 0, stream>>>(fc1part, fc1_b, flags, fc1o);
    fc2_kernel<<<256, 640, 0, stream>>>(fc1o, fc2_w, fc2_b, flags, d_out);
}